// Round 8
// baseline (130.495 us; speedup 1.0000x reference)
//
#include <hip/hip_runtime.h>
#include <hip/hip_cooperative_groups.h>
#include <math.h>

namespace cg = cooperative_groups;

// DecoderGATLayer — single cooperative kernel, 4 phases / 3 grid.syncs. f32.
// S=192, B=2, E=512, H=2, D=256, BH=4.
// Dead inputs: ex_entity, ex_relation, Wxe, Wxr (reference deletes `we`).
// score[bh,t,s] = A[s&3][i] + B[t&3][s] + C[s&3][i] - C[s&3][j] + ba,
//   i = bh*48 + (t>>2), j = (t&3)*48 + (s>>2)
// q/k projections folded into tables via u = W^T wa_slice (round-7, verified).

#define SS 192
// ws float offsets
#define VO  0          // [384][256], row = s*2+b
#define EO  98304
#define TO  196608     // 12*192
#define OO  198912     // attn out [384][512], row = 2t+b, col = h*256+d
#define WTV 395520     // 131072 floats
#define WTE 526592
#define WTO 657664     // 262144 floats
// end 919808 floats = 3.5 MB

__device__ __forceinline__ float wave_reduce_add(float p) {
    #pragma unroll
    for (int off = 32; off >= 1; off >>= 1) p += __shfl_xor(p, off, 64);
    return p;
}

__global__ __launch_bounds__(1024) void k_all(
    const float* __restrict__ query, const float* __restrict__ entity,
    const float* __restrict__ Wq, const float* __restrict__ bq,
    const float* __restrict__ Wk, const float* __restrict__ bk,
    const float* __restrict__ Wv, const float* __restrict__ bv,
    const float* __restrict__ We, const float* __restrict__ be,
    const float* __restrict__ Wa, const float* __restrict__ ba_p,
    const float* __restrict__ Wo, const float* __restrict__ bo,
    float* __restrict__ ws, float* __restrict__ out)
{
    cg::grid_group grid = cg::this_grid();
    __shared__ __align__(16) float lds[8192];   // 32 KB, reused per phase
    __shared__ __align__(16) float sp4[768];    // softmax rows / uo buffer
    int blk = blockIdx.x;                       // 0..191
    int tid = threadIdx.x;                      // 0..1023
    int wv   = __builtin_amdgcn_readfirstlane(tid >> 6);
    int lane = tid & 63;

    // ================= phase A: transposes + score tables =================
    if (blk < 128) {
        // WT4[k4*D + d] = W4[d*128 + k4]; coalesced read, scattered write
        int o = blk * 1024 + tid;              // 0..131071
        const float4* src; float4* dst; int idx; int D;
        if (o < 32768)      { src = (const float4*)Wv; dst = (float4*)(ws + WTV); idx = o;         D = 256; }
        else if (o < 65536) { src = (const float4*)We; dst = (float4*)(ws + WTE); idx = o - 32768; D = 256; }
        else                { src = (const float4*)Wo; dst = (float4*)(ws + WTO); idx = o - 65536; D = 512; }
        int d  = idx >> 7;
        int k4 = idx & 127;
        dst[k4 * D + d] = src[idx];
    } else if (blk < 136) {
        // A/B tables via u = W^T wa_slice  (verified round 7)
        float* red = lds;          // [16][512]
        float* uo  = sp4;          // [512]
        int tab = blk - 128;                   // 0..7
        int p   = (tab < 4) ? tab : tab - 4;
        int b   = p >> 1, h = p & 1;
        const float* wa   = Wa + ((tab < 4) ? 0 : 256);
        const float* W    = h ? We : ((tab < 4) ? Wq : Wk);
        const float* bias = h ? be : ((tab < 4) ? bq : bk);
        const float* x    = h ? entity : query;

        float u8[8];
        #pragma unroll
        for (int i = 0; i < 8; i++) u8[i] = 0.f;
        #pragma unroll 4
        for (int dd = 0; dd < 16; dd++) {
            int d = wv * 16 + dd;
            float wad = wa[d];                                  // wave-uniform
            const float4* Wr = (const float4*)(W + (size_t)d * 512);
            float4 w0 = Wr[lane * 2], w1 = Wr[lane * 2 + 1];    // coalesced
            u8[0] += wad * w0.x; u8[1] += wad * w0.y; u8[2] += wad * w0.z; u8[3] += wad * w0.w;
            u8[4] += wad * w1.x; u8[5] += wad * w1.y; u8[6] += wad * w1.z; u8[7] += wad * w1.w;
        }
        #pragma unroll
        for (int i = 0; i < 8; i++) red[wv * 512 + lane * 8 + i] = u8[i];
        __syncthreads();
        if (tid < 512) {
            float s = 0.f;
            #pragma unroll
            for (int w = 0; w < 16; w++) s += red[w * 512 + tid];
            uo[tid] = s;
        }
        __syncthreads();
        if (tid < 256) red[tid] = wa[tid] * bias[tid];
        __syncthreads();
        for (int o = 128; o >= 1; o >>= 1) {
            if (tid < o) red[tid] += red[tid + o];
            __syncthreads();
        }
        float off = red[0];

        const float4* u4 = (const float4*)uo;
        float4 ua = u4[lane * 2], ub = u4[lane * 2 + 1];
        for (int rr = 0; rr < 12; rr++) {
            int r = wv * 12 + rr;
            const float4* xr = (const float4*)(x + (size_t)(r * 2 + b) * 512);
            float4 a0 = xr[lane * 2], a1 = xr[lane * 2 + 1];
            float pp = a0.x*ua.x + a0.y*ua.y + a0.z*ua.z + a0.w*ua.w
                     + a1.x*ub.x + a1.y*ub.y + a1.z*ub.z + a1.w*ub.w;
            pp = wave_reduce_add(pp);
            if (lane == 0) ws[TO + tab * SS + r] = pp + off;
        }
    } else if (blk < 140) {
        // C tables: C[m][i] = Wa[512:768) . entity[i*2+(m>>1)][(m&1)*256 ..]
        int m = blk - 136;                     // 0..3
        float4 wa4 = ((const float4*)(Wa + 512))[lane];
        for (int rr = 0; rr < 12; rr++) {
            int i = wv * 12 + rr;
            const float4* er = (const float4*)(entity
                + (size_t)(i * 2 + (m >> 1)) * 512 + (m & 1) * 256);
            float4 e4 = er[lane];
            float pp = e4.x*wa4.x + e4.y*wa4.y + e4.z*wa4.z + e4.w*wa4.w;
            pp = wave_reduce_add(pp);
            if (lane == 0) ws[TO + (8 + m) * SS + i] = pp;
        }
    }
    grid.sync();

    // ================= phase B: v,e projections (split-k x4) =================
    {
        int m  = blk / 96;                     // 0: v(query), 1: e(entity)
        int r0 = (blk % 96) * 4;
        int chunk = __builtin_amdgcn_readfirstlane(tid >> 8);
        int d  = tid & 255;
        const float*  A    = m ? entity : query;
        const float*  bias = m ? be : bv;
        const float4* WT   = (const float4*)(ws + (m ? WTE : WTV));
        float*        dst  = ws + (m ? EO : VO);
        const float4* A4   = (const float4*)A;   // [384][128]

        float acc[4];
        #pragma unroll
        for (int r = 0; r < 4; r++) acc[r] = 0.f;

        int k4b = chunk * 32;
        #pragma unroll 4
        for (int i = 0; i < 32; i++) {
            int k4 = k4b + i;
            float4 w = WT[k4 * 256 + d];
            #pragma unroll
            for (int r = 0; r < 4; r++) {
                float4 a = A4[(r0 + r) * 128 + k4];   // wave-uniform -> s_load
                acc[r] += a.x * w.x + a.y * w.y + a.z * w.z + a.w * w.w;
            }
        }
        #pragma unroll
        for (int r = 0; r < 4; r++) lds[(chunk * 4 + r) * 256 + d] = acc[r];
        __syncthreads();
        {
            int idx = tid;                     // r*256 + d
            int rr  = idx >> 8, dd = idx & 255;
            float v = lds[idx] + lds[1024 + idx] + lds[2048 + idx] + lds[3072 + idx];
            dst[(size_t)(r0 + rr) * 256 + dd] = v + bias[dd];
        }
    }
    grid.sync();

    // ================= phase C: attention (softmax + PV, split-s x4) =================
    {
        int bh = blk & 3;
        int tg = blk >> 2;                     // 0..47 ; t = tg*4 + ti
        int b = bh >> 1, h = bh & 1;
        const float* T = ws + TO;
        float ba = ba_p[0];

        __syncthreads();   // lds reuse hazard from phase B's final reads
        if (wv < 4) {
            int ti = wv;
            int i_idx = bh * 48 + tg;
            float sc[3]; float mx = -1e30f;
            #pragma unroll
            for (int i = 0; i < 3; i++) {
                int s_ = lane + 64 * i;
                int m  = s_ & 3;
                int j  = ti * 48 + (s_ >> 2);
                float xv = T[m * SS + i_idx] + T[(4 + ti) * SS + s_]
                         + T[(8 + m) * SS + i_idx] - T[(8 + m) * SS + j] + ba;
                xv = (xv >= 0.f) ? xv : 0.01f * xv;      // leaky_relu
                sc[i] = xv; mx = fmaxf(mx, xv);
            }
            #pragma unroll
            for (int o = 32; o >= 1; o >>= 1) mx = fmaxf(mx, __shfl_xor(mx, o, 64));
            float sum = 0.f;
            #pragma unroll
            for (int i = 0; i < 3; i++) { sc[i] = __expf(sc[i] - mx); sum += sc[i]; }
            sum = wave_reduce_add(sum);
            float inv = 1.f / sum;
            #pragma unroll
            for (int i = 0; i < 3; i++) sp4[ti * SS + lane + 64 * i] = sc[i] * inv;
        }
        __syncthreads();

        // PV: thread (sq = tid>>8, dd = tid&255); each load feeds 4 t's
        int sq = __builtin_amdgcn_readfirstlane(tid >> 8);
        int dd = tid & 255;
        const float* src = ws + (h ? EO : VO) + b * 256 + dd;
        float a[4] = {0.f, 0.f, 0.f, 0.f};
        #pragma unroll 4
        for (int s2 = 0; s2 < 48; s2++) {
            int s = sq * 48 + s2;
            float xv = src[(size_t)s * 512];
            #pragma unroll
            for (int ti = 0; ti < 4; ti++) a[ti] += sp4[ti * SS + s] * xv;
        }
        #pragma unroll
        for (int ti = 0; ti < 4; ti++) lds[sq * 1024 + ti * 256 + dd] = a[ti];
        __syncthreads();
        {
            int ti = tid >> 8, d2 = tid & 255;
            int idx = ti * 256 + d2;
            float v = lds[idx] + lds[1024 + idx] + lds[2048 + idx] + lds[3072 + idx];
            int t = tg * 4 + ti;
            ws[OO + (size_t)(2 * t + b) * 512 + h * 256 + d2] = v;
        }
    }
    grid.sync();

    // ================= phase D: output fc (split-k x4) =================
    {
        int rg = blk >> 1;                     // 0..95
        int cg = blk & 1;
        int r0 = rg * 4;
        int chunk = __builtin_amdgcn_readfirstlane(tid >> 8);
        int col = cg * 256 + (tid & 255);
        const float4* A4 = (const float4*)(ws + OO);    // [384][128]
        const float4* WT = (const float4*)(ws + WTO);   // [128][512]

        float acc[4];
        #pragma unroll
        for (int r = 0; r < 4; r++) acc[r] = 0.f;

        int k4b = chunk * 32;
        #pragma unroll 4
        for (int i = 0; i < 32; i++) {
            int k4 = k4b + i;
            float4 w = WT[k4 * 512 + col];
            #pragma unroll
            for (int r = 0; r < 4; r++) {
                float4 a = A4[(r0 + r) * 128 + k4];   // wave-uniform -> s_load
                acc[r] += a.x * w.x + a.y * w.y + a.z * w.z + a.w * w.w;
            }
        }
        __syncthreads();   // lds reuse hazard from phase C
        int dl = tid & 255;
        #pragma unroll
        for (int r = 0; r < 4; r++) lds[(chunk * 4 + r) * 256 + dl] = acc[r];
        __syncthreads();
        {
            int idx = tid;                     // r*256 + dl
            int rr = idx >> 8, d2 = idx & 255;
            float v = lds[idx] + lds[1024 + idx] + lds[2048 + idx] + lds[3072 + idx];
            out[(size_t)(r0 + rr) * 512 + cg * 256 + d2] = v + bo[cg * 256 + d2];
        }
    }
}

extern "C" void kernel_launch(void* const* d_in, const int* in_sizes, int n_in,
                              void* d_out, int out_size, void* d_ws, size_t ws_size,
                              hipStream_t stream) {
    const float* query  = (const float*)d_in[0];
    const float* entity = (const float*)d_in[1];
    // d_in[2] ex_entity, d_in[3] ex_relation: dead
    const float* Wq = (const float*)d_in[4];  const float* bq = (const float*)d_in[5];
    const float* Wk = (const float*)d_in[6];  const float* bk = (const float*)d_in[7];
    const float* Wv = (const float*)d_in[8];  const float* bv = (const float*)d_in[9];
    const float* We = (const float*)d_in[10]; const float* be = (const float*)d_in[11];
    // d_in[12..15] dead
    const float* Wa = (const float*)d_in[16]; const float* ba = (const float*)d_in[17];
    const float* Wo = (const float*)d_in[18]; const float* bo = (const float*)d_in[19];
    float* ws  = (float*)d_ws;
    float* out = (float*)d_out;

    void* args[] = {
        (void*)&query, (void*)&entity,
        (void*)&Wq, (void*)&bq, (void*)&Wk, (void*)&bk,
        (void*)&Wv, (void*)&bv, (void*)&We, (void*)&be,
        (void*)&Wa, (void*)&ba, (void*)&Wo, (void*)&bo,
        (void*)&ws, (void*)&out
    };
    hipLaunchCooperativeKernel((const void*)k_all, dim3(192), dim3(1024),
                               args, 0, stream);
}

// Round 9
// 48.903 us; speedup vs baseline: 2.6685x; 2.6685x over previous
//
#include <hip/hip_runtime.h>
#include <math.h>

// DecoderGATLayer — 4 flat kernels, round-8 phase bodies (verified), no grid.sync.
// S=192, B=2, E=512, H=2, D=256, BH=4. f32.
// Dead inputs: ex_entity, ex_relation, Wxe, Wxr (reference deletes `we`).
// score[bh,t,s] = A[s&3][i] + B[t&3][s] + C[s&3][i] - C[s&3][j] + ba,
//   i = bh*48 + (t>>2), j = (t&3)*48 + (s>>2)
// q/k projections folded into tables via u = W^T wa_slice (verified round 7).

#define SS 192
// ws float offsets
#define VO  0          // [384][256], row = s*2+b
#define EO  98304
#define TO  196608     // 12*192
#define OO  198912     // attn out [384][512], row = 2t+b, col = h*256+d
#define WTV 395520     // 131072 floats
#define WTE 526592
#define WTO 657664     // 262144 floats
// end 919808 floats = 3.5 MB

__device__ __forceinline__ float wave_reduce_add(float p) {
    #pragma unroll
    for (int off = 32; off >= 1; off >>= 1) p += __shfl_xor(p, off, 64);
    return p;
}

// ===== K1: transposes (blk 0..127) + A/B tables (128..135) + C tables (136..139)
__global__ __launch_bounds__(1024) void k_prep(
    const float* __restrict__ query, const float* __restrict__ entity,
    const float* __restrict__ Wq, const float* __restrict__ bq,
    const float* __restrict__ Wk, const float* __restrict__ bk,
    const float* __restrict__ Wv, const float* __restrict__ We,
    const float* __restrict__ be, const float* __restrict__ Wa,
    const float* __restrict__ Wo, float* __restrict__ ws)
{
    __shared__ __align__(16) float red[16 * 512];   // 32 KB
    __shared__ __align__(16) float uo[516];
    int blk = blockIdx.x;
    int tid = threadIdx.x;

    if (blk < 128) {
        // WT4[k4*D + d] = W4[d*128 + k4]; coalesced read, scattered write
        int o = blk * 1024 + tid;              // 0..131071
        const float4* src; float4* dst; int idx; int D;
        if (o < 32768)      { src = (const float4*)Wv; dst = (float4*)(ws + WTV); idx = o;         D = 256; }
        else if (o < 65536) { src = (const float4*)We; dst = (float4*)(ws + WTE); idx = o - 32768; D = 256; }
        else                { src = (const float4*)Wo; dst = (float4*)(ws + WTO); idx = o - 65536; D = 512; }
        int d  = idx >> 7;
        int k4 = idx & 127;
        dst[k4 * D + d] = src[idx];
        return;
    }

    int wv   = __builtin_amdgcn_readfirstlane(tid >> 6);
    int lane = tid & 63;

    if (blk < 136) {
        // A/B tables via u = W^T wa_slice
        int tab = blk - 128;                   // 0..7
        int p   = (tab < 4) ? tab : tab - 4;
        int b   = p >> 1, h = p & 1;
        const float* wa   = Wa + ((tab < 4) ? 0 : 256);
        const float* W    = h ? We : ((tab < 4) ? Wq : Wk);
        const float* bias = h ? be : ((tab < 4) ? bq : bk);
        const float* x    = h ? entity : query;

        float u8[8];
        #pragma unroll
        for (int i = 0; i < 8; i++) u8[i] = 0.f;
        #pragma unroll 4
        for (int dd = 0; dd < 16; dd++) {
            int d = wv * 16 + dd;
            float wad = wa[d];                                  // wave-uniform
            const float4* Wr = (const float4*)(W + (size_t)d * 512);
            float4 w0 = Wr[lane * 2], w1 = Wr[lane * 2 + 1];    // coalesced
            u8[0] += wad * w0.x; u8[1] += wad * w0.y; u8[2] += wad * w0.z; u8[3] += wad * w0.w;
            u8[4] += wad * w1.x; u8[5] += wad * w1.y; u8[6] += wad * w1.z; u8[7] += wad * w1.w;
        }
        #pragma unroll
        for (int i = 0; i < 8; i++) red[wv * 512 + lane * 8 + i] = u8[i];
        __syncthreads();
        if (tid < 512) {
            float s = 0.f;
            #pragma unroll
            for (int w = 0; w < 16; w++) s += red[w * 512 + tid];
            uo[tid] = s;
        }
        __syncthreads();
        if (tid < 256) red[tid] = wa[tid] * bias[tid];
        __syncthreads();
        for (int o = 128; o >= 1; o >>= 1) {
            if (tid < o) red[tid] += red[tid + o];
            __syncthreads();
        }
        float off = red[0];

        const float4* u4 = (const float4*)uo;
        float4 ua = u4[lane * 2], ub = u4[lane * 2 + 1];
        for (int rr = 0; rr < 12; rr++) {
            int r = wv * 12 + rr;
            const float4* xr = (const float4*)(x + (size_t)(r * 2 + b) * 512);
            float4 a0 = xr[lane * 2], a1 = xr[lane * 2 + 1];
            float pp = a0.x*ua.x + a0.y*ua.y + a0.z*ua.z + a0.w*ua.w
                     + a1.x*ub.x + a1.y*ub.y + a1.z*ub.z + a1.w*ub.w;
            pp = wave_reduce_add(pp);
            if (lane == 0) ws[TO + tab * SS + r] = pp + off;
        }
        return;
    }

    // C tables: C[m][i] = Wa[512:768) . entity[i*2+(m>>1)][(m&1)*256 ..]
    {
        int m = blk - 136;                     // 0..3
        float4 wa4 = ((const float4*)(Wa + 512))[lane];
        for (int rr = 0; rr < 12; rr++) {
            int i = wv * 12 + rr;
            const float4* er = (const float4*)(entity
                + (size_t)(i * 2 + (m >> 1)) * 512 + (m & 1) * 256);
            float4 e4 = er[lane];
            float pp = e4.x*wa4.x + e4.y*wa4.y + e4.z*wa4.z + e4.w*wa4.w;
            pp = wave_reduce_add(pp);
            if (lane == 0) ws[TO + (8 + m) * SS + i] = pp;
        }
    }
}

// ===== K2: v,e projections. 192 blocks x 1024 thr, 4 rows/block, split-k x4.
__global__ __launch_bounds__(1024) void k_proj(
    const float* __restrict__ query, const float* __restrict__ entity,
    const float* __restrict__ bv, const float* __restrict__ be,
    float* __restrict__ ws)
{
    __shared__ float lds[4096];
    int blk = blockIdx.x;
    int m  = blk / 96;                     // 0: v(query), 1: e(entity)
    int r0 = (blk % 96) * 4;
    int tid = threadIdx.x;
    int chunk = __builtin_amdgcn_readfirstlane(tid >> 8);
    int d  = tid & 255;
    const float*  A    = m ? entity : query;
    const float*  bias = m ? be : bv;
    const float4* WT   = (const float4*)(ws + (m ? WTE : WTV));
    float*        dst  = ws + (m ? EO : VO);
    const float4* A4   = (const float4*)A;   // [384][128]

    float acc[4];
    #pragma unroll
    for (int r = 0; r < 4; r++) acc[r] = 0.f;

    int k4b = chunk * 32;
    #pragma unroll 8
    for (int i = 0; i < 32; i++) {
        int k4 = k4b + i;
        float4 w = WT[k4 * 256 + d];
        #pragma unroll
        for (int r = 0; r < 4; r++) {
            float4 a = A4[(r0 + r) * 128 + k4];   // wave-uniform -> s_load
            acc[r] += a.x * w.x + a.y * w.y + a.z * w.z + a.w * w.w;
        }
    }
    #pragma unroll
    for (int r = 0; r < 4; r++) lds[(chunk * 4 + r) * 256 + d] = acc[r];
    __syncthreads();
    {
        int idx = tid;                     // r*256 + d
        int rr  = idx >> 8, dd = idx & 255;
        float v = lds[idx] + lds[1024 + idx] + lds[2048 + idx] + lds[3072 + idx];
        dst[(size_t)(r0 + rr) * 256 + dd] = v + bias[dd];
    }
}

// ===== K3: attention. 192 blocks (bh, tg) x 1024 thr, split-s x4.
__global__ __launch_bounds__(1024) void k_attn(
    const float* __restrict__ ba_p, float* __restrict__ ws)
{
    __shared__ __align__(16) float lds[4096];
    __shared__ __align__(16) float sp4[768];
    int blk = blockIdx.x;
    int bh = blk & 3;
    int tg = blk >> 2;                     // 0..47 ; t = tg*4 + ti
    int b = bh >> 1, h = bh & 1;
    const float* T = ws + TO;
    float ba = ba_p[0];
    int tid  = threadIdx.x;
    int wv   = __builtin_amdgcn_readfirstlane(tid >> 6);
    int lane = tid & 63;

    if (wv < 4) {
        int ti = wv;
        int i_idx = bh * 48 + tg;
        float sc[3]; float mx = -1e30f;
        #pragma unroll
        for (int i = 0; i < 3; i++) {
            int s_ = lane + 64 * i;
            int m  = s_ & 3;
            int j  = ti * 48 + (s_ >> 2);
            float xv = T[m * SS + i_idx] + T[(4 + ti) * SS + s_]
                     + T[(8 + m) * SS + i_idx] - T[(8 + m) * SS + j] + ba;
            xv = (xv >= 0.f) ? xv : 0.01f * xv;      // leaky_relu
            sc[i] = xv; mx = fmaxf(mx, xv);
        }
        #pragma unroll
        for (int o = 32; o >= 1; o >>= 1) mx = fmaxf(mx, __shfl_xor(mx, o, 64));
        float sum = 0.f;
        #pragma unroll
        for (int i = 0; i < 3; i++) { sc[i] = __expf(sc[i] - mx); sum += sc[i]; }
        sum = wave_reduce_add(sum);
        float inv = 1.f / sum;
        #pragma unroll
        for (int i = 0; i < 3; i++) sp4[ti * SS + lane + 64 * i] = sc[i] * inv;
    }
    __syncthreads();

    // PV: thread (sq = tid>>8, dd = tid&255); each load feeds 4 t's
    int sq = __builtin_amdgcn_readfirstlane(tid >> 8);
    int dd = tid & 255;
    const float* src = ws + (h ? EO : VO) + b * 256 + dd;
    float a[4] = {0.f, 0.f, 0.f, 0.f};
    #pragma unroll 8
    for (int s2 = 0; s2 < 48; s2++) {
        int s = sq * 48 + s2;
        float xv = src[(size_t)s * 512];
        #pragma unroll
        for (int ti = 0; ti < 4; ti++) a[ti] += sp4[ti * SS + s] * xv;
    }
    #pragma unroll
    for (int ti = 0; ti < 4; ti++) lds[sq * 1024 + ti * 256 + dd] = a[ti];
    __syncthreads();
    {
        int ti = tid >> 8, d2 = tid & 255;
        int idx = ti * 256 + d2;
        float v = lds[idx] + lds[1024 + idx] + lds[2048 + idx] + lds[3072 + idx];
        int t = tg * 4 + ti;
        ws[OO + (size_t)(2 * t + b) * 512 + h * 256 + d2] = v;
    }
}

// ===== K4: output fc. 192 blocks x 1024 thr, split-k x4.
__global__ __launch_bounds__(1024) void k_out(
    const float* __restrict__ bo, const float* __restrict__ ws,
    float* __restrict__ out)
{
    __shared__ float lds[4096];
    int blk = blockIdx.x;
    int rg = blk >> 1;                     // 0..95
    int cg = blk & 1;
    int r0 = rg * 4;
    int tid = threadIdx.x;
    int chunk = __builtin_amdgcn_readfirstlane(tid >> 8);
    int col = cg * 256 + (tid & 255);
    const float4* A4 = (const float4*)(ws + OO);    // [384][128]
    const float4* WT = (const float4*)(ws + WTO);   // [128][512]

    float acc[4];
    #pragma unroll
    for (int r = 0; r < 4; r++) acc[r] = 0.f;

    int k4b = chunk * 32;
    #pragma unroll 8
    for (int i = 0; i < 32; i++) {
        int k4 = k4b + i;
        float4 w = WT[k4 * 512 + col];
        #pragma unroll
        for (int r = 0; r < 4; r++) {
            float4 a = A4[(r0 + r) * 128 + k4];   // wave-uniform -> s_load
            acc[r] += a.x * w.x + a.y * w.y + a.z * w.z + a.w * w.w;
        }
    }
    int dl = tid & 255;
    #pragma unroll
    for (int r = 0; r < 4; r++) lds[(chunk * 4 + r) * 256 + dl] = acc[r];
    __syncthreads();
    {
        int idx = tid;                     // r*256 + dl
        int rr = idx >> 8, d2 = idx & 255;
        float v = lds[idx] + lds[1024 + idx] + lds[2048 + idx] + lds[3072 + idx];
        out[(size_t)(r0 + rr) * 512 + cg * 256 + d2] = v + bo[cg * 256 + d2];
    }
}

extern "C" void kernel_launch(void* const* d_in, const int* in_sizes, int n_in,
                              void* d_out, int out_size, void* d_ws, size_t ws_size,
                              hipStream_t stream) {
    const float* query  = (const float*)d_in[0];
    const float* entity = (const float*)d_in[1];
    // d_in[2] ex_entity, d_in[3] ex_relation: dead
    const float* Wq = (const float*)d_in[4];  const float* bq = (const float*)d_in[5];
    const float* Wk = (const float*)d_in[6];  const float* bk = (const float*)d_in[7];
    const float* Wv = (const float*)d_in[8];  const float* bv = (const float*)d_in[9];
    const float* We = (const float*)d_in[10]; const float* be = (const float*)d_in[11];
    // d_in[12..15] dead
    const float* Wa = (const float*)d_in[16]; const float* ba = (const float*)d_in[17];
    const float* Wo = (const float*)d_in[18]; const float* bo = (const float*)d_in[19];
    float* ws  = (float*)d_ws;
    float* out = (float*)d_out;

    hipLaunchKernelGGL(k_prep, dim3(140), dim3(1024), 0, stream,
                       query, entity, Wq, bq, Wk, bk, Wv, We, be, Wa, Wo, ws);
    hipLaunchKernelGGL(k_proj, dim3(192), dim3(1024), 0, stream,
                       query, entity, bv, be, ws);
    hipLaunchKernelGGL(k_attn, dim3(192), dim3(1024), 0, stream, ba, ws);
    hipLaunchKernelGGL(k_out,  dim3(192), dim3(1024), 0, stream, bo, ws, out);
}